// Round 1
// baseline (4152.495 us; speedup 1.0000x reference)
//
#include <hip/hip_runtime.h>

#define NPT  4096
#define NBLK 256
#define NTHR 1024

constexpr float EPSV   = 1e-4f;
constexpr float LN2F   = 0.69314718055994531f;
constexpr float E2     = EPSV * LN2F;          // eps*ln2
constexpr float INV_E2 = 1.0f / E2;            // 1/(eps*ln2)
constexpr float S_U    = 4.0f / LN2F;          // uniformity scale: t = (-4xn_j -4xn_i +4 x.x)/ln2

// LDS layout (floats):
//   x01 : [0,8192)        float2[4096]
//   x2  : [8192,12288)    float [4096]
//   y01 : [12288,20480)   float2[4096]
//   y2  : [20480,24576)   float [4096]
//   G   : [24576,28672)   float [4096]   per-step scaled column potential
//   part: [28672,28928)   float2[128]    (m,s) partials: [local_row][half]
#define SMEM_FLOATS 28928
#define SMEM_BYTES  (SMEM_FLOATS * 4)

__device__ __forceinline__ float fexp2(float x) { return __builtin_amdgcn_exp2f(x); }
__device__ __forceinline__ float flog2(float x) { return __builtin_amdgcn_logf(x); }

__device__ __forceinline__ void grid_barrier(unsigned* ctr, unsigned target) {
    __threadfence();            // release my stores device-wide
    __syncthreads();
    if (threadIdx.x == 0) {
        __hip_atomic_fetch_add(ctr, 1u, __ATOMIC_RELEASE, __HIP_MEMORY_SCOPE_AGENT);
        while (__hip_atomic_load(ctr, __ATOMIC_RELAXED, __HIP_MEMORY_SCOPE_AGENT) < target) {
            __builtin_amdgcn_s_sleep(2);
        }
        __threadfence();        // acquire: invalidate stale L1/L2 lines
    }
    __syncthreads();
}

// One wave computes per-lane chunked log2-LSE for 4 rows over 2048 columns (half of 4096),
// then butterfly-reduces across 64 lanes and writes (m,s) partials to LDS.
template<bool ISU>
__device__ __forceinline__ void run_task(
    const float2* __restrict__ c01, const float* __restrict__ c2v,
    const float*  __restrict__ G,
    const float2* __restrict__ r01, const float* __restrict__ r2v,
    int r0g, int half, int lane, float scale, float2* part, int lr0)
{
    float xs0[4], xs1[4], xs2[4];
#pragma unroll
    for (int r = 0; r < 4; ++r) {
        float2 q = r01[r0g + r]; float qz = r2v[r0g + r];
        xs0[r] = q.x * scale; xs1[r] = q.y * scale; xs2[r] = qz * scale;
    }
    float m[4], s[4];
#pragma unroll
    for (int r = 0; r < 4; ++r) { m[r] = -1e30f; s[r] = 0.0f; }

    const int cbase = half * 2048 + lane;
#pragma unroll
    for (int chunk = 0; chunk < 2; ++chunk) {
        float av[4][16];
        float mc[4];
#pragma unroll
        for (int r = 0; r < 4; ++r) mc[r] = -1e30f;
#pragma unroll
        for (int k = 0; k < 16; ++k) {
            const int j = cbase + chunk * 1024 + k * 64;
            const float2 cc = c01[j];
            const float  cz = c2v[j];
            const float  gj = G[j];
#pragma unroll
            for (int r = 0; r < 4; ++r) {
                float a = fmaf(xs0[r], cc.x, gj);
                a = fmaf(xs1[r], cc.y, a);
                a = fmaf(xs2[r], cz, a);
                if (ISU) a = (j == r0g + r) ? -1e30f : a;   // mask diagonal
                av[r][k] = a;
                mc[r] = fmaxf(mc[r], a);
            }
        }
#pragma unroll
        for (int r = 0; r < 4; ++r) {
            float sc = 0.0f;
#pragma unroll
            for (int k = 0; k < 16; ++k) sc += fexp2(av[r][k] - mc[r]);
            float mn = fmaxf(m[r], mc[r]);
            s[r] = s[r] * fexp2(m[r] - mn) + sc * fexp2(mc[r] - mn);
            m[r] = mn;
        }
    }
    // 64-lane butterfly merge of (m,s) per row
#pragma unroll
    for (int off = 1; off < 64; off <<= 1) {
#pragma unroll
        for (int r = 0; r < 4; ++r) {
            float mo = __shfl_xor(m[r], off, 64);
            float so = __shfl_xor(s[r], off, 64);
            float mn = fmaxf(m[r], mo);
            s[r] = s[r] * fexp2(m[r] - mn) + so * fexp2(mo - mn);
            m[r] = mn;
        }
    }
    if (lane == 0) {
        part[(lr0 + 0) * 2 + half] = make_float2(m[0], s[0]);
        part[(lr0 + 1) * 2 + half] = make_float2(m[1], s[1]);
        part[(lr0 + 2) * 2 + half] = make_float2(m[2], s[2]);
        part[(lr0 + 3) * 2 + half] = make_float2(m[3], s[3]);
    }
}

__global__ void sink_init(float* __restrict__ ws) {
    int t = blockIdx.x * blockDim.x + threadIdx.x;
    if (t < NPT) {
        ws[t]          = 0.0f;   // f
        ws[4096 + t]   = 0.0f;   // g
        ws[8192 + t]   = 0.0f;   // px0
        ws[16384 + t]  = 0.0f;   // py0
    }
    if (t == 0) *(unsigned*)(ws + 40960) = 0u;   // barrier counter
}

__global__ __launch_bounds__(NTHR) void sink_main(
    const float* __restrict__ xin, const float* __restrict__ yin,
    float* __restrict__ ws, float* __restrict__ out)
{
    extern __shared__ float smem[];
    float2* x01 = (float2*)smem;
    float*  x2  = smem + 8192;
    float2* y01 = (float2*)(smem + 12288);
    float*  y2  = smem + 20480;
    float*  G   = smem + 24576;
    float2* part = (float2*)(smem + 28672);

    float* f    = ws;
    float* g    = ws + 4096;
    float* px0  = ws + 8192;
    float* px1  = ws + 12288;
    float* py0  = ws + 16384;
    float* py1  = ws + 20480;
    float* ffin = ws + 24576;
    float* fxv  = ws + 28672;
    float* fyv  = ws + 32768;
    float* uls  = ws + 36864;
    unsigned* ctr = (unsigned*)(ws + 40960);

    const int tid  = threadIdx.x;
    const int b    = blockIdx.x;
    const int wave = tid >> 6;
    const int lane = tid & 63;

    // Stage both point clouds into LDS (SoA). p_q stride 3, p_gt stride 4 (use xyz).
    for (int i = tid; i < NPT; i += NTHR) {
        float a0 = xin[3 * i], a1 = xin[3 * i + 1], a2v = xin[3 * i + 2];
        x01[i] = make_float2(a0, a1); x2[i] = a2v;
        float4 v = ((const float4*)yin)[i];
        y01[i] = make_float2(v.x, v.y); y2[i] = v.z;
    }
    __syncthreads();

    for (int h = 0; h <= 40; ++h) {
        // ---- decode this block's chain for this step ----
        bool rows_x, cols_x, isU = false, avg = false;
        const float* pot; float* outp; float scale = INV_E2;
        int row0g, rows_pb;
        if (h == 0) {
            if (b < 128)      { rows_x = true;  cols_x = false; pot = g;    outp = f;    rows_pb = 32; row0g = b * 32; }
            else if (b < 192) { rows_x = true;  cols_x = true;  pot = px0;  outp = px1;  avg = true; rows_pb = 64; row0g = (b - 128) * 64; }
            else              { rows_x = true;  cols_x = true;  pot = nullptr; outp = uls; isU = true; scale = S_U; rows_pb = 64; row0g = (b - 192) * 64; }
        } else if (h == 40) {
            if (b < 128)      { rows_x = true;  cols_x = false; pot = g;    outp = ffin; rows_pb = 32; row0g = b * 32; }
            else if (b < 192) { rows_x = true;  cols_x = true;  pot = px0;  outp = fxv;  rows_pb = 64; row0g = (b - 128) * 64; }
            else              { rows_x = false; cols_x = false; pot = py0;  outp = fyv;  rows_pb = 64; row0g = (b - 192) * 64; }
        } else if (h & 1) {
            int k = (h - 1) >> 1;   // yy iteration
            if (b < 128) { rows_x = false; cols_x = true;  pot = f; outp = g; rows_pb = 32; row0g = b * 32; }
            else         { rows_x = false; cols_x = false; pot = (k & 1) ? py1 : py0; outp = (k & 1) ? py0 : py1; avg = true; rows_pb = 32; row0g = (b - 128) * 32; }
        } else {
            int k = h >> 1;         // xx iteration (h=2..38 -> k=1..19)
            if (b < 128) { rows_x = true; cols_x = false; pot = g; outp = f; rows_pb = 32; row0g = b * 32; }
            else         { rows_x = true; cols_x = true;  pot = (k & 1) ? px1 : px0; outp = (k & 1) ? px0 : px1; avg = true; rows_pb = 32; row0g = (b - 128) * 32; }
        }

        // ---- stage scaled column potential G into LDS ----
        const float2* c01 = cols_x ? x01 : y01;
        const float*  c2v = cols_x ? x2  : y2;
        for (int j = tid; j < NPT; j += NTHR) {
            float2 p2 = c01[j]; float z = c2v[j];
            float cn = 0.5f * (p2.x * p2.x + p2.y * p2.y) + 0.5f * z * z;
            float pv = pot ? pot[j] : 0.0f;
            G[j] = (pv - cn) * scale;
        }
        __syncthreads();

        // ---- wave tasks: 4 rows x 2048 cols each ----
        const float2* r01 = rows_x ? x01 : y01;
        const float*  r2v = rows_x ? x2  : y2;
        const int ntask = rows_pb >> 1;
        for (int t = wave; t < ntask; t += 16) {
            int grp = t >> 1, half = t & 1;
            int lr0 = grp << 2;
            int r0g = row0g + lr0;
            if (isU) run_task<true >(c01, c2v, G, r01, r2v, r0g, half, lane, scale, part, lr0);
            else     run_task<false>(c01, c2v, G, r01, r2v, r0g, half, lane, scale, part, lr0);
        }
        __syncthreads();

        // ---- finalize: merge halves, apply row term, write potential ----
        if (tid < rows_pb) {
            float2 pa = part[tid * 2 + 0], pb = part[tid * 2 + 1];
            float mm = fmaxf(pa.x, pb.x);
            float ss = pa.y * fexp2(pa.x - mm) + pb.y * fexp2(pb.x - mm);
            int rg = row0g + tid;
            float2 q = r01[rg]; float qz = r2v[rg];
            float rn = 0.5f * (q.x * q.x + q.y * q.y) + 0.5f * qz * qz;
            float lse2 = mm + flog2(ss) - rn * scale;    // + X_i
            float val;
            if (isU) {
                val = lse2;                               // per-row log2 LSE for uniformity
            } else {
                val = -E2 * (lse2 - 12.0f);               // -eps*(lse - ln M), log2(4096)=12
                if (avg) val = 0.5f * (pot[rg] + val);
            }
            outp[rg] = val;
        }

        grid_barrier(ctr, 256u * (unsigned)(h + 1));
    }

    // ---- final reduction (block 0 only) ----
    if (b == 0) {
        float sf = 0.f, sg = 0.f, sx = 0.f, sy = 0.f, um = -1e30f, us = 0.f;
        for (int i = tid; i < NPT; i += NTHR) {
            sf += ffin[i]; sg += g[i]; sx += fxv[i]; sy += fyv[i];
            float v = uls[i];
            float mn = fmaxf(um, v);
            us = us * fexp2(um - mn) + fexp2(v - mn);
            um = mn;
        }
#pragma unroll
        for (int off = 1; off < 64; off <<= 1) {
            sf += __shfl_xor(sf, off, 64);
            sg += __shfl_xor(sg, off, 64);
            sx += __shfl_xor(sx, off, 64);
            sy += __shfl_xor(sy, off, 64);
            float mo = __shfl_xor(um, off, 64);
            float so = __shfl_xor(us, off, 64);
            float mn = fmaxf(um, mo);
            us = us * fexp2(um - mn) + so * fexp2(mo - mn);
            um = mn;
        }
        __syncthreads();
        if (lane == 0) {
            float* red = smem;
            red[wave * 6 + 0] = sf; red[wave * 6 + 1] = sg; red[wave * 6 + 2] = sx;
            red[wave * 6 + 3] = sy; red[wave * 6 + 4] = um; red[wave * 6 + 5] = us;
        }
        __syncthreads();
        if (tid == 0) {
            float* red = smem;
            float Sf = 0, Sg = 0, Sx = 0, Sy = 0, Um = -1e30f, Us = 0;
            for (int w = 0; w < 16; ++w) {
                Sf += red[w * 6 + 0]; Sg += red[w * 6 + 1];
                Sx += red[w * 6 + 2]; Sy += red[w * 6 + 3];
                float mo = red[w * 6 + 4], so = red[w * 6 + 5];
                float mn = fmaxf(Um, mo);
                Us = Us * fexp2(Um - mn) + so * fexp2(mo - mn);
                Um = mn;
            }
            float mean = (Sf + Sg - Sx - Sy) * (1.0f / 4096.0f);
            float U = LN2F * (Um + flog2(Us)) - logf(4096.0f * 4095.0f);
            out[0] = mean + U;
        }
    }
}

extern "C" void kernel_launch(void* const* d_in, const int* in_sizes, int n_in,
                              void* d_out, int out_size, void* d_ws, size_t ws_size,
                              hipStream_t stream) {
    const float* x = (const float*)d_in[0];
    const float* y = (const float*)d_in[1];
    float* ws  = (float*)d_ws;
    float* out = (float*)d_out;

    // allow >64KB dynamic LDS (113 KB); ignore error if unsupported
    (void)hipFuncSetAttribute((const void*)sink_main,
                              hipFuncAttributeMaxDynamicSharedMemorySize, SMEM_BYTES);

    sink_init<<<4, 1024, 0, stream>>>(ws);
    sink_main<<<NBLK, NTHR, SMEM_BYTES, stream>>>(x, y, ws, out);
}

// Round 2
// 1020.614 us; speedup vs baseline: 4.0686x; 4.0686x over previous
//
#include <hip/hip_runtime.h>

#define NPT  4096
#define NBLK 256
#define NTHR 1024

constexpr float EPSV   = 1e-4f;
constexpr float LN2F   = 0.69314718055994531f;
constexpr float E2     = EPSV * LN2F;          // eps*ln2
constexpr float INV_E2 = 1.0f / E2;            // 1/(eps*ln2)
constexpr float S_U    = 4.0f / LN2F;          // uniformity scale

// LDS layout (floats):
//   x01 : [0,8192)        float2[4096]
//   x2  : [8192,12288)    float [4096]
//   y01 : [12288,20480)   float2[4096]
//   y2  : [20480,24576)   float [4096]
//   G   : [24576,28672)   float [4096]   per-step scaled column potential
//   part: [28672,28928)   float2[128]    (m,s) partials
#define SMEM_FLOATS 28928
#define SMEM_BYTES  (SMEM_FLOATS * 4)

__device__ __forceinline__ float fexp2(float x) { return __builtin_amdgcn_exp2f(x); }
__device__ __forceinline__ float flog2(float x) { return __builtin_amdgcn_logf(x); }

// system-scope (sc0 sc1) relaxed accessors: bypass non-coherent XCD L2s,
// hit the coherent memory-side Infinity Cache. No wbl2/inv fences needed.
__device__ __forceinline__ float gload(const float* p) {
    return __hip_atomic_load(p, __ATOMIC_RELAXED, __HIP_MEMORY_SCOPE_SYSTEM);
}
__device__ __forceinline__ void gstore(float* p, float v) {
    __hip_atomic_store(p, v, __ATOMIC_RELAXED, __HIP_MEMORY_SCOPE_SYSTEM);
}

// Fence-free grid barrier.
// __syncthreads() drains each wave's vmcnt before s_barrier, so every wave's
// sc0sc1 stores are at the coherent point before thread 0 announces arrival.
// 16 counters in distinct 64B lines avoid same-line RMW serialization.
__device__ __forceinline__ void grid_barrier(unsigned* ctr, unsigned target, int b) {
    asm volatile("s_waitcnt vmcnt(0)" ::: "memory");
    __syncthreads();
    if (threadIdx.x == 0) {
        __hip_atomic_fetch_add(&ctr[(b & 15) * 16], 1u,
                               __ATOMIC_RELAXED, __HIP_MEMORY_SCOPE_SYSTEM);
        for (;;) {
            unsigned tot = 0;
#pragma unroll
            for (int i = 0; i < 16; ++i)
                tot += __hip_atomic_load(&ctr[i * 16],
                                         __ATOMIC_RELAXED, __HIP_MEMORY_SCOPE_SYSTEM);
            if (tot >= target) break;
            __builtin_amdgcn_s_sleep(1);
        }
    }
    __syncthreads();
}

// One wave: chunked log2-LSE for 4 rows over 2048 columns (half of 4096),
// butterfly-reduce across 64 lanes, write (m,s) partials to LDS.
template<bool ISU>
__device__ __forceinline__ void run_task(
    const float2* __restrict__ c01, const float* __restrict__ c2v,
    const float*  __restrict__ G,
    const float2* __restrict__ r01, const float* __restrict__ r2v,
    int r0g, int half, int lane, float scale, float2* part, int lr0)
{
    float xs0[4], xs1[4], xs2[4];
#pragma unroll
    for (int r = 0; r < 4; ++r) {
        float2 q = r01[r0g + r]; float qz = r2v[r0g + r];
        xs0[r] = q.x * scale; xs1[r] = q.y * scale; xs2[r] = qz * scale;
    }
    float m[4], s[4];
#pragma unroll
    for (int r = 0; r < 4; ++r) { m[r] = -1e30f; s[r] = 0.0f; }

    const int cbase = half * 2048 + lane;
#pragma unroll
    for (int chunk = 0; chunk < 2; ++chunk) {
        float av[4][16];
        float mc[4];
#pragma unroll
        for (int r = 0; r < 4; ++r) mc[r] = -1e30f;
#pragma unroll
        for (int k = 0; k < 16; ++k) {
            const int j = cbase + chunk * 1024 + k * 64;
            const float2 cc = c01[j];
            const float  cz = c2v[j];
            const float  gj = G[j];
#pragma unroll
            for (int r = 0; r < 4; ++r) {
                float a = fmaf(xs0[r], cc.x, gj);
                a = fmaf(xs1[r], cc.y, a);
                a = fmaf(xs2[r], cz, a);
                if (ISU) a = (j == r0g + r) ? -1e30f : a;   // mask diagonal
                av[r][k] = a;
                mc[r] = fmaxf(mc[r], a);
            }
        }
#pragma unroll
        for (int r = 0; r < 4; ++r) {
            float sc = 0.0f;
#pragma unroll
            for (int k = 0; k < 16; ++k) sc += fexp2(av[r][k] - mc[r]);
            float mn = fmaxf(m[r], mc[r]);
            s[r] = s[r] * fexp2(m[r] - mn) + sc * fexp2(mc[r] - mn);
            m[r] = mn;
        }
    }
#pragma unroll
    for (int off = 1; off < 64; off <<= 1) {
#pragma unroll
        for (int r = 0; r < 4; ++r) {
            float mo = __shfl_xor(m[r], off, 64);
            float so = __shfl_xor(s[r], off, 64);
            float mn = fmaxf(m[r], mo);
            s[r] = s[r] * fexp2(m[r] - mn) + so * fexp2(mo - mn);
            m[r] = mn;
        }
    }
    if (lane == 0) {
        part[(lr0 + 0) * 2 + half] = make_float2(m[0], s[0]);
        part[(lr0 + 1) * 2 + half] = make_float2(m[1], s[1]);
        part[(lr0 + 2) * 2 + half] = make_float2(m[2], s[2]);
        part[(lr0 + 3) * 2 + half] = make_float2(m[3], s[3]);
    }
}

__global__ void sink_init(float* __restrict__ ws) {
    int t = blockIdx.x * blockDim.x + threadIdx.x;
    if (t < NPT) {
        gstore(ws + t, 0.0f);           // f
        gstore(ws + 4096 + t, 0.0f);    // g
        gstore(ws + 8192 + t, 0.0f);    // px0
        gstore(ws + 16384 + t, 0.0f);   // py0
    }
    if (t < 256) {
        __hip_atomic_store((unsigned*)(ws + 40960) + t, 0u,
                           __ATOMIC_RELAXED, __HIP_MEMORY_SCOPE_SYSTEM);
    }
}

__global__ __launch_bounds__(NTHR) void sink_main(
    const float* __restrict__ xin, const float* __restrict__ yin,
    float* __restrict__ ws, float* __restrict__ out)
{
    extern __shared__ float smem[];
    float2* x01 = (float2*)smem;
    float*  x2  = smem + 8192;
    float2* y01 = (float2*)(smem + 12288);
    float*  y2  = smem + 20480;
    float*  G   = smem + 24576;
    float2* part = (float2*)(smem + 28672);

    float* f    = ws;
    float* g    = ws + 4096;
    float* px0  = ws + 8192;
    float* px1  = ws + 12288;
    float* py0  = ws + 16384;
    float* py1  = ws + 20480;
    float* ffin = ws + 24576;
    float* fxv  = ws + 28672;
    float* fyv  = ws + 32768;
    float* uls  = ws + 36864;
    unsigned* ctr = (unsigned*)(ws + 40960);

    const int tid  = threadIdx.x;
    const int b    = blockIdx.x;
    const int wave = tid >> 6;
    const int lane = tid & 63;

    // Stage both point clouds into LDS (SoA). p_q stride 3, p_gt stride 4.
    for (int i = tid; i < NPT; i += NTHR) {
        float a0 = xin[3 * i], a1 = xin[3 * i + 1], a2v = xin[3 * i + 2];
        x01[i] = make_float2(a0, a1); x2[i] = a2v;
        float4 v = ((const float4*)yin)[i];
        y01[i] = make_float2(v.x, v.y); y2[i] = v.z;
    }
    __syncthreads();

    for (int h = 0; h <= 40; ++h) {
        // ---- decode this block's chain for this step ----
        bool rows_x, cols_x, isU = false, avg = false;
        const float* pot; float* outp; float scale = INV_E2;
        int row0g, rows_pb;
        if (h == 0) {
            if (b < 128)      { rows_x = true;  cols_x = false; pot = g;    outp = f;    rows_pb = 32; row0g = b * 32; }
            else if (b < 192) { rows_x = true;  cols_x = true;  pot = px0;  outp = px1;  avg = true; rows_pb = 64; row0g = (b - 128) * 64; }
            else              { rows_x = true;  cols_x = true;  pot = nullptr; outp = uls; isU = true; scale = S_U; rows_pb = 64; row0g = (b - 192) * 64; }
        } else if (h == 40) {
            if (b < 128)      { rows_x = true;  cols_x = false; pot = g;    outp = ffin; rows_pb = 32; row0g = b * 32; }
            else if (b < 192) { rows_x = true;  cols_x = true;  pot = px0;  outp = fxv;  rows_pb = 64; row0g = (b - 128) * 64; }
            else              { rows_x = false; cols_x = false; pot = py0;  outp = fyv;  rows_pb = 64; row0g = (b - 192) * 64; }
        } else if (h & 1) {
            int k = (h - 1) >> 1;   // yy iteration
            if (b < 128) { rows_x = false; cols_x = true;  pot = f; outp = g; rows_pb = 32; row0g = b * 32; }
            else         { rows_x = false; cols_x = false; pot = (k & 1) ? py1 : py0; outp = (k & 1) ? py0 : py1; avg = true; rows_pb = 32; row0g = (b - 128) * 32; }
        } else {
            int k = h >> 1;         // xx iteration
            if (b < 128) { rows_x = true; cols_x = false; pot = g; outp = f; rows_pb = 32; row0g = b * 32; }
            else         { rows_x = true; cols_x = true;  pot = (k & 1) ? px1 : px0; outp = (k & 1) ? px0 : px1; avg = true; rows_pb = 32; row0g = (b - 128) * 32; }
        }

        // ---- stage scaled column potential G into LDS (coherent loads) ----
        const float2* c01 = cols_x ? x01 : y01;
        const float*  c2v = cols_x ? x2  : y2;
        for (int j = tid; j < NPT; j += NTHR) {
            float2 p2 = c01[j]; float z = c2v[j];
            float cn = 0.5f * (p2.x * p2.x + p2.y * p2.y) + 0.5f * z * z;
            float pv = pot ? gload(pot + j) : 0.0f;
            G[j] = (pv - cn) * scale;
        }
        __syncthreads();

        // ---- wave tasks: 4 rows x 2048 cols each ----
        const float2* r01 = rows_x ? x01 : y01;
        const float*  r2v = rows_x ? x2  : y2;
        const int ntask = rows_pb >> 1;
        for (int t = wave; t < ntask; t += 16) {
            int grp = t >> 1, half = t & 1;
            int lr0 = grp << 2;
            int r0g = row0g + lr0;
            if (isU) run_task<true >(c01, c2v, G, r01, r2v, r0g, half, lane, scale, part, lr0);
            else     run_task<false>(c01, c2v, G, r01, r2v, r0g, half, lane, scale, part, lr0);
        }
        __syncthreads();

        // ---- finalize: merge halves, apply row term, write potential ----
        if (tid < rows_pb) {
            float2 pa = part[tid * 2 + 0], pb = part[tid * 2 + 1];
            float mm = fmaxf(pa.x, pb.x);
            float ss = pa.y * fexp2(pa.x - mm) + pb.y * fexp2(pb.x - mm);
            int rg = row0g + tid;
            float2 q = r01[rg]; float qz = r2v[rg];
            float rn = 0.5f * (q.x * q.x + q.y * q.y) + 0.5f * qz * qz;
            float lse2 = mm + flog2(ss) - rn * scale;    // + X_i
            float val;
            if (isU) {
                val = lse2;
            } else {
                val = -E2 * (lse2 - 12.0f);               // log2(4096)=12
                if (avg) val = 0.5f * (gload(pot + rg) + val);
            }
            gstore(outp + rg, val);
        }

        grid_barrier(ctr, 256u * (unsigned)(h + 1), b);
    }

    // ---- final reduction (block 0 only) ----
    if (b == 0) {
        float sf = 0.f, sg = 0.f, sx = 0.f, sy = 0.f, um = -1e30f, us = 0.f;
        for (int i = tid; i < NPT; i += NTHR) {
            sf += gload(ffin + i); sg += gload(g + i);
            sx += gload(fxv + i);  sy += gload(fyv + i);
            float v = gload(uls + i);
            float mn = fmaxf(um, v);
            us = us * fexp2(um - mn) + fexp2(v - mn);
            um = mn;
        }
#pragma unroll
        for (int off = 1; off < 64; off <<= 1) {
            sf += __shfl_xor(sf, off, 64);
            sg += __shfl_xor(sg, off, 64);
            sx += __shfl_xor(sx, off, 64);
            sy += __shfl_xor(sy, off, 64);
            float mo = __shfl_xor(um, off, 64);
            float so = __shfl_xor(us, off, 64);
            float mn = fmaxf(um, mo);
            us = us * fexp2(um - mn) + so * fexp2(mo - mn);
            um = mn;
        }
        __syncthreads();
        if (lane == 0) {
            float* red = smem;
            red[wave * 6 + 0] = sf; red[wave * 6 + 1] = sg; red[wave * 6 + 2] = sx;
            red[wave * 6 + 3] = sy; red[wave * 6 + 4] = um; red[wave * 6 + 5] = us;
        }
        __syncthreads();
        if (tid == 0) {
            float* red = smem;
            float Sf = 0, Sg = 0, Sx = 0, Sy = 0, Um = -1e30f, Us = 0;
            for (int w = 0; w < 16; ++w) {
                Sf += red[w * 6 + 0]; Sg += red[w * 6 + 1];
                Sx += red[w * 6 + 2]; Sy += red[w * 6 + 3];
                float mo = red[w * 6 + 4], so = red[w * 6 + 5];
                float mn = fmaxf(Um, mo);
                Us = Us * fexp2(Um - mn) + so * fexp2(mo - mn);
                Um = mn;
            }
            float mean = (Sf + Sg - Sx - Sy) * (1.0f / 4096.0f);
            float U = LN2F * (Um + flog2(Us)) - logf(4096.0f * 4095.0f);
            out[0] = mean + U;
        }
    }
}

extern "C" void kernel_launch(void* const* d_in, const int* in_sizes, int n_in,
                              void* d_out, int out_size, void* d_ws, size_t ws_size,
                              hipStream_t stream) {
    const float* x = (const float*)d_in[0];
    const float* y = (const float*)d_in[1];
    float* ws  = (float*)d_ws;
    float* out = (float*)d_out;

    (void)hipFuncSetAttribute((const void*)sink_main,
                              hipFuncAttributeMaxDynamicSharedMemorySize, SMEM_BYTES);

    sink_init<<<4, 1024, 0, stream>>>(ws);
    sink_main<<<NBLK, NTHR, SMEM_BYTES, stream>>>(x, y, ws, out);
}

// Round 3
// 1018.255 us; speedup vs baseline: 4.0781x; 1.0023x over previous
//
#include <hip/hip_runtime.h>

#define NPT  4096
#define NBLK 256
#define NTHR 1024

constexpr float EPSV   = 1e-4f;
constexpr float LN2F   = 0.69314718055994531f;
constexpr float E2     = EPSV * LN2F;          // eps*ln2
constexpr float INV_E2 = 1.0f / E2;            // 1/(eps*ln2)
constexpr float S_U    = 4.0f / LN2F;          // uniformity scale

// LDS layout (floats):
//   x01 : [0,8192)        float2[4096]
//   x2  : [8192,12288)    float [4096]
//   y01 : [12288,20480)   float2[4096]
//   y2  : [20480,24576)   float [4096]
//   G   : [24576,28672)   float [4096]   per-step scaled column potential
//   part: [28672,28928)   float2[128]    (m,s) partials
#define SMEM_FLOATS 28928
#define SMEM_BYTES  (SMEM_FLOATS * 4)

__device__ __forceinline__ float fexp2(float x) { return __builtin_amdgcn_exp2f(x); }
__device__ __forceinline__ float flog2(float x) { return __builtin_amdgcn_logf(x); }

// system-scope (sc0 sc1) relaxed accessors: bypass non-coherent XCD L2s,
// hit the coherent memory-side Infinity Cache. No wbl2/inv fences needed.
__device__ __forceinline__ float gload(const float* p) {
    return __hip_atomic_load(p, __ATOMIC_RELAXED, __HIP_MEMORY_SCOPE_SYSTEM);
}
__device__ __forceinline__ void gstore(float* p, float v) {
    __hip_atomic_store(p, v, __ATOMIC_RELAXED, __HIP_MEMORY_SCOPE_SYSTEM);
}

// Fence-free grid barrier.
// __syncthreads() drains each wave's vmcnt before s_barrier, so every wave's
// sc0sc1 stores are at the coherent point before thread 0 announces arrival.
// 16 counters in distinct 64B lines avoid same-line RMW serialization.
__device__ __forceinline__ void grid_barrier(unsigned* ctr, unsigned target, int b) {
    asm volatile("s_waitcnt vmcnt(0)" ::: "memory");
    __syncthreads();
    if (threadIdx.x == 0) {
        __hip_atomic_fetch_add(&ctr[(b & 15) * 16], 1u,
                               __ATOMIC_RELAXED, __HIP_MEMORY_SCOPE_SYSTEM);
        for (;;) {
            unsigned tot = 0;
#pragma unroll
            for (int i = 0; i < 16; ++i)
                tot += __hip_atomic_load(&ctr[i * 16],
                                         __ATOMIC_RELAXED, __HIP_MEMORY_SCOPE_SYSTEM);
            if (tot >= target) break;
            __builtin_amdgcn_s_sleep(1);
        }
    }
    __syncthreads();
}

// One wave: chunked log2-LSE for 4 rows over 2048 columns (half of 4096),
// butterfly-reduce across 64 lanes, write (m,s) partials to LDS.
template<bool ISU>
__device__ __forceinline__ void run_task(
    const float2* __restrict__ c01, const float* __restrict__ c2v,
    const float*  __restrict__ G,
    const float2* __restrict__ r01, const float* __restrict__ r2v,
    int r0g, int half, int lane, float scale, float2* part, int lr0)
{
    float xs0[4], xs1[4], xs2[4];
#pragma unroll
    for (int r = 0; r < 4; ++r) {
        float2 q = r01[r0g + r]; float qz = r2v[r0g + r];
        xs0[r] = q.x * scale; xs1[r] = q.y * scale; xs2[r] = qz * scale;
    }
    float m[4], s[4];
#pragma unroll
    for (int r = 0; r < 4; ++r) { m[r] = -1e30f; s[r] = 0.0f; }

    const int cbase = half * 2048 + lane;
#pragma unroll
    for (int chunk = 0; chunk < 2; ++chunk) {
        float av[4][16];
        float mc[4];
#pragma unroll
        for (int r = 0; r < 4; ++r) mc[r] = -1e30f;
#pragma unroll
        for (int k = 0; k < 16; ++k) {
            const int j = cbase + chunk * 1024 + k * 64;
            const float2 cc = c01[j];
            const float  cz = c2v[j];
            const float  gj = G[j];
#pragma unroll
            for (int r = 0; r < 4; ++r) {
                float a = fmaf(xs0[r], cc.x, gj);
                a = fmaf(xs1[r], cc.y, a);
                a = fmaf(xs2[r], cz, a);
                if (ISU) a = (j == r0g + r) ? -1e30f : a;   // mask diagonal
                av[r][k] = a;
                mc[r] = fmaxf(mc[r], a);
            }
        }
#pragma unroll
        for (int r = 0; r < 4; ++r) {
            float sc = 0.0f;
#pragma unroll
            for (int k = 0; k < 16; ++k) sc += fexp2(av[r][k] - mc[r]);
            float mn = fmaxf(m[r], mc[r]);
            s[r] = s[r] * fexp2(m[r] - mn) + sc * fexp2(mc[r] - mn);
            m[r] = mn;
        }
    }
#pragma unroll
    for (int off = 1; off < 64; off <<= 1) {
#pragma unroll
        for (int r = 0; r < 4; ++r) {
            float mo = __shfl_xor(m[r], off, 64);
            float so = __shfl_xor(s[r], off, 64);
            float mn = fmaxf(m[r], mo);
            s[r] = s[r] * fexp2(m[r] - mn) + so * fexp2(mo - mn);
            m[r] = mn;
        }
    }
    if (lane == 0) {
        part[(lr0 + 0) * 2 + half] = make_float2(m[0], s[0]);
        part[(lr0 + 1) * 2 + half] = make_float2(m[1], s[1]);
        part[(lr0 + 2) * 2 + half] = make_float2(m[2], s[2]);
        part[(lr0 + 3) * 2 + half] = make_float2(m[3], s[3]);
    }
}

__global__ void sink_init(float* __restrict__ ws) {
    int t = blockIdx.x * blockDim.x + threadIdx.x;
    if (t < NPT) {
        gstore(ws + t, 0.0f);           // f
        gstore(ws + 4096 + t, 0.0f);    // g
        gstore(ws + 8192 + t, 0.0f);    // px0
        gstore(ws + 16384 + t, 0.0f);   // py0
    }
    if (t < 256) {
        __hip_atomic_store((unsigned*)(ws + 40960) + t, 0u,
                           __ATOMIC_RELAXED, __HIP_MEMORY_SCOPE_SYSTEM);
    }
}

// LDS caps us at 1 block/CU (16 waves = 4 waves/EU). Declare exactly that so
// the register allocator gets the full budget (~512 VGPR cap) instead of the
// default 64-VGPR cap — the av[4][16] chunk buffer must NOT spill to scratch.
__global__ __launch_bounds__(NTHR, 4) void sink_main(
    const float* __restrict__ xin, const float* __restrict__ yin,
    float* __restrict__ ws, float* __restrict__ out)
{
    extern __shared__ float smem[];
    float2* x01 = (float2*)smem;
    float*  x2  = smem + 8192;
    float2* y01 = (float2*)(smem + 12288);
    float*  y2  = smem + 20480;
    float*  G   = smem + 24576;
    float2* part = (float2*)(smem + 28672);

    float* f    = ws;
    float* g    = ws + 4096;
    float* px0  = ws + 8192;
    float* px1  = ws + 12288;
    float* py0  = ws + 16384;
    float* py1  = ws + 20480;
    float* ffin = ws + 24576;
    float* fxv  = ws + 28672;
    float* fyv  = ws + 32768;
    float* uls  = ws + 36864;
    unsigned* ctr = (unsigned*)(ws + 40960);

    const int tid  = threadIdx.x;
    const int b    = blockIdx.x;
    const int wave = tid >> 6;
    const int lane = tid & 63;

    // Stage both point clouds into LDS (SoA). p_q stride 3, p_gt stride 4.
    for (int i = tid; i < NPT; i += NTHR) {
        float a0 = xin[3 * i], a1 = xin[3 * i + 1], a2v = xin[3 * i + 2];
        x01[i] = make_float2(a0, a1); x2[i] = a2v;
        float4 v = ((const float4*)yin)[i];
        y01[i] = make_float2(v.x, v.y); y2[i] = v.z;
    }
    __syncthreads();

    for (int h = 0; h <= 40; ++h) {
        // ---- decode this block's chain for this step ----
        bool rows_x, cols_x, isU = false, avg = false;
        const float* pot; float* outp; float scale = INV_E2;
        int row0g, rows_pb;
        if (h == 0) {
            if (b < 128)      { rows_x = true;  cols_x = false; pot = g;    outp = f;    rows_pb = 32; row0g = b * 32; }
            else if (b < 192) { rows_x = true;  cols_x = true;  pot = px0;  outp = px1;  avg = true; rows_pb = 64; row0g = (b - 128) * 64; }
            else              { rows_x = true;  cols_x = true;  pot = nullptr; outp = uls; isU = true; scale = S_U; rows_pb = 64; row0g = (b - 192) * 64; }
        } else if (h == 40) {
            if (b < 128)      { rows_x = true;  cols_x = false; pot = g;    outp = ffin; rows_pb = 32; row0g = b * 32; }
            else if (b < 192) { rows_x = true;  cols_x = true;  pot = px0;  outp = fxv;  rows_pb = 64; row0g = (b - 128) * 64; }
            else              { rows_x = false; cols_x = false; pot = py0;  outp = fyv;  rows_pb = 64; row0g = (b - 192) * 64; }
        } else if (h & 1) {
            int k = (h - 1) >> 1;   // yy iteration
            if (b < 128) { rows_x = false; cols_x = true;  pot = f; outp = g; rows_pb = 32; row0g = b * 32; }
            else         { rows_x = false; cols_x = false; pot = (k & 1) ? py1 : py0; outp = (k & 1) ? py0 : py1; avg = true; rows_pb = 32; row0g = (b - 128) * 32; }
        } else {
            int k = h >> 1;         // xx iteration
            if (b < 128) { rows_x = true; cols_x = false; pot = g; outp = f; rows_pb = 32; row0g = b * 32; }
            else         { rows_x = true; cols_x = true;  pot = (k & 1) ? px1 : px0; outp = (k & 1) ? px0 : px1; avg = true; rows_pb = 32; row0g = (b - 128) * 32; }
        }

        // ---- stage scaled column potential G into LDS (coherent loads) ----
        const float2* c01 = cols_x ? x01 : y01;
        const float*  c2v = cols_x ? x2  : y2;
        for (int j = tid; j < NPT; j += NTHR) {
            float2 p2 = c01[j]; float z = c2v[j];
            float cn = 0.5f * (p2.x * p2.x + p2.y * p2.y) + 0.5f * z * z;
            float pv = pot ? gload(pot + j) : 0.0f;
            G[j] = (pv - cn) * scale;
        }
        __syncthreads();

        // ---- wave tasks: 4 rows x 2048 cols each ----
        const float2* r01 = rows_x ? x01 : y01;
        const float*  r2v = rows_x ? x2  : y2;
        const int ntask = rows_pb >> 1;
        for (int t = wave; t < ntask; t += 16) {
            int grp = t >> 1, half = t & 1;
            int lr0 = grp << 2;
            int r0g = row0g + lr0;
            if (isU) run_task<true >(c01, c2v, G, r01, r2v, r0g, half, lane, scale, part, lr0);
            else     run_task<false>(c01, c2v, G, r01, r2v, r0g, half, lane, scale, part, lr0);
        }
        __syncthreads();

        // ---- finalize: merge halves, apply row term, write potential ----
        if (tid < rows_pb) {
            float2 pa = part[tid * 2 + 0], pb = part[tid * 2 + 1];
            float mm = fmaxf(pa.x, pb.x);
            float ss = pa.y * fexp2(pa.x - mm) + pb.y * fexp2(pb.x - mm);
            int rg = row0g + tid;
            float2 q = r01[rg]; float qz = r2v[rg];
            float rn = 0.5f * (q.x * q.x + q.y * q.y) + 0.5f * qz * qz;
            float lse2 = mm + flog2(ss) - rn * scale;    // + X_i
            float val;
            if (isU) {
                val = lse2;
            } else {
                val = -E2 * (lse2 - 12.0f);               // log2(4096)=12
                if (avg) val = 0.5f * (gload(pot + rg) + val);
            }
            gstore(outp + rg, val);
        }

        grid_barrier(ctr, 256u * (unsigned)(h + 1), b);
    }

    // ---- final reduction (block 0 only) ----
    if (b == 0) {
        float sf = 0.f, sg = 0.f, sx = 0.f, sy = 0.f, um = -1e30f, us = 0.f;
        for (int i = tid; i < NPT; i += NTHR) {
            sf += gload(ffin + i); sg += gload(g + i);
            sx += gload(fxv + i);  sy += gload(fyv + i);
            float v = gload(uls + i);
            float mn = fmaxf(um, v);
            us = us * fexp2(um - mn) + fexp2(v - mn);
            um = mn;
        }
#pragma unroll
        for (int off = 1; off < 64; off <<= 1) {
            sf += __shfl_xor(sf, off, 64);
            sg += __shfl_xor(sg, off, 64);
            sx += __shfl_xor(sx, off, 64);
            sy += __shfl_xor(sy, off, 64);
            float mo = __shfl_xor(um, off, 64);
            float so = __shfl_xor(us, off, 64);
            float mn = fmaxf(um, mo);
            us = us * fexp2(um - mn) + so * fexp2(mo - mn);
            um = mn;
        }
        __syncthreads();
        if (lane == 0) {
            float* red = smem;
            red[wave * 6 + 0] = sf; red[wave * 6 + 1] = sg; red[wave * 6 + 2] = sx;
            red[wave * 6 + 3] = sy; red[wave * 6 + 4] = um; red[wave * 6 + 5] = us;
        }
        __syncthreads();
        if (tid == 0) {
            float* red = smem;
            float Sf = 0, Sg = 0, Sx = 0, Sy = 0, Um = -1e30f, Us = 0;
            for (int w = 0; w < 16; ++w) {
                Sf += red[w * 6 + 0]; Sg += red[w * 6 + 1];
                Sx += red[w * 6 + 2]; Sy += red[w * 6 + 3];
                float mo = red[w * 6 + 4], so = red[w * 6 + 5];
                float mn = fmaxf(Um, mo);
                Us = Us * fexp2(Um - mn) + so * fexp2(mo - mn);
                Um = mn;
            }
            float mean = (Sf + Sg - Sx - Sy) * (1.0f / 4096.0f);
            float U = LN2F * (Um + flog2(Us)) - logf(4096.0f * 4095.0f);
            out[0] = mean + U;
        }
    }
}

extern "C" void kernel_launch(void* const* d_in, const int* in_sizes, int n_in,
                              void* d_out, int out_size, void* d_ws, size_t ws_size,
                              hipStream_t stream) {
    const float* x = (const float*)d_in[0];
    const float* y = (const float*)d_in[1];
    float* ws  = (float*)d_ws;
    float* out = (float*)d_out;

    (void)hipFuncSetAttribute((const void*)sink_main,
                              hipFuncAttributeMaxDynamicSharedMemorySize, SMEM_BYTES);

    sink_init<<<4, 1024, 0, stream>>>(ws);
    sink_main<<<NBLK, NTHR, SMEM_BYTES, stream>>>(x, y, ws, out);
}

// Round 4
// 620.558 us; speedup vs baseline: 6.6916x; 1.6409x over previous
//
#include <hip/hip_runtime.h>

#define NPT  4096
#define NBLK 256
#define NTHR 1024

constexpr float EPSV   = 1e-4f;
constexpr float LN2F   = 0.69314718055994531f;
constexpr float E2     = EPSV * LN2F;          // eps*ln2
constexpr float INV_E2 = 1.0f / E2;            // 1/(eps*ln2)
constexpr float S_U    = 4.0f / LN2F;          // uniformity scale

// LDS layout (floats):
//   x01 : [0,8192)        float2[4096]
//   x2  : [8192,12288)    float [4096]
//   y01 : [12288,20480)   float2[4096]
//   y2  : [20480,24576)   float [4096]
//   G   : [24576,28672)   float [4096]   per-step scaled column potential
//   part: [28672,28928)   float2[128]    (m,s) partials
#define SMEM_FLOATS 28928
#define SMEM_BYTES  (SMEM_FLOATS * 4)

__device__ __forceinline__ float fexp2(float x) { return __builtin_amdgcn_exp2f(x); }
__device__ __forceinline__ float flog2(float x) { return __builtin_amdgcn_logf(x); }

// system-scope (sc0 sc1) relaxed accessors: bypass non-coherent XCD L2s,
// hit the coherent memory-side Infinity Cache. No wbl2/inv fences needed.
__device__ __forceinline__ float gload(const float* p) {
    return __hip_atomic_load(p, __ATOMIC_RELAXED, __HIP_MEMORY_SCOPE_SYSTEM);
}
__device__ __forceinline__ void gstore(float* p, float v) {
    __hip_atomic_store(p, v, __ATOMIC_RELAXED, __HIP_MEMORY_SCOPE_SYSTEM);
}

// Fence-free GROUP barrier (128 blocks per group; xy chain and xx/yy chain
// never read each other's state during the iteration, verified per-step).
// __syncthreads() drains vmcnt before s_barrier, so all sc0sc1 stores are at
// the coherent point before thread 0 announces arrival. 16 counters in
// distinct 64B lines avoid same-line RMW serialization.
__device__ __forceinline__ void group_barrier(unsigned* base, unsigned target, int b) {
    asm volatile("s_waitcnt vmcnt(0)" ::: "memory");
    __syncthreads();
    if (threadIdx.x == 0) {
        __hip_atomic_fetch_add(&base[(b & 15) * 16], 1u,
                               __ATOMIC_RELAXED, __HIP_MEMORY_SCOPE_SYSTEM);
        for (;;) {
            unsigned tot = 0;
#pragma unroll
            for (int i = 0; i < 16; ++i)
                tot += __hip_atomic_load(&base[i * 16],
                                         __ATOMIC_RELAXED, __HIP_MEMORY_SCOPE_SYSTEM);
            if (tot >= target) break;
            __builtin_amdgcn_s_sleep(1);
        }
    }
    __syncthreads();
}

// One wave: chunked log2-LSE for 2 rows over 2048 columns (half of 4096),
// butterfly-reduce across 64 lanes, write (m,s) partials to LDS.
// 2 rows (not 4) keeps the live set (av[2][16]=32 + ~25 misc) under the
// 64-VGPR budget — R2/R3 spilled ~2 GB/launch of scratch with av[4][16].
template<bool ISU>
__device__ __forceinline__ void run_task(
    const float2* __restrict__ c01, const float* __restrict__ c2v,
    const float*  __restrict__ G,
    const float2* __restrict__ r01, const float* __restrict__ r2v,
    int r0g, int half, int lane, float scale, float2* part, int lr0)
{
    float xs0[2], xs1[2], xs2[2];
#pragma unroll
    for (int r = 0; r < 2; ++r) {
        float2 q = r01[r0g + r]; float qz = r2v[r0g + r];
        xs0[r] = q.x * scale; xs1[r] = q.y * scale; xs2[r] = qz * scale;
    }
    float m[2], s[2];
#pragma unroll
    for (int r = 0; r < 2; ++r) { m[r] = -1e30f; s[r] = 0.0f; }

    const int cbase = half * 2048 + lane;
#pragma unroll
    for (int chunk = 0; chunk < 2; ++chunk) {
        float av[2][16];
        float mc[2];
#pragma unroll
        for (int r = 0; r < 2; ++r) mc[r] = -1e30f;
#pragma unroll
        for (int k = 0; k < 16; ++k) {
            const int j = cbase + chunk * 1024 + k * 64;
            const float2 cc = c01[j];
            const float  cz = c2v[j];
            const float  gj = G[j];
#pragma unroll
            for (int r = 0; r < 2; ++r) {
                float a = fmaf(xs0[r], cc.x, gj);
                a = fmaf(xs1[r], cc.y, a);
                a = fmaf(xs2[r], cz, a);
                if (ISU) a = (j == r0g + r) ? -1e30f : a;   // mask diagonal
                av[r][k] = a;
                mc[r] = fmaxf(mc[r], a);
            }
        }
#pragma unroll
        for (int r = 0; r < 2; ++r) {
            float sc = 0.0f;
#pragma unroll
            for (int k = 0; k < 16; ++k) sc += fexp2(av[r][k] - mc[r]);
            float mn = fmaxf(m[r], mc[r]);
            s[r] = s[r] * fexp2(m[r] - mn) + sc * fexp2(mc[r] - mn);
            m[r] = mn;
        }
    }
#pragma unroll
    for (int off = 1; off < 64; off <<= 1) {
#pragma unroll
        for (int r = 0; r < 2; ++r) {
            float mo = __shfl_xor(m[r], off, 64);
            float so = __shfl_xor(s[r], off, 64);
            float mn = fmaxf(m[r], mo);
            s[r] = s[r] * fexp2(m[r] - mn) + so * fexp2(mo - mn);
            m[r] = mn;
        }
    }
    if (lane == 0) {
        part[(lr0 + 0) * 2 + half] = make_float2(m[0], s[0]);
        part[(lr0 + 1) * 2 + half] = make_float2(m[1], s[1]);
    }
}

__global__ void sink_init(float* __restrict__ ws) {
    int t = blockIdx.x * blockDim.x + threadIdx.x;
    if (t < NPT) {
        gstore(ws + t, 0.0f);           // f
        gstore(ws + 4096 + t, 0.0f);    // g
        gstore(ws + 8192 + t, 0.0f);    // px0
        gstore(ws + 16384 + t, 0.0f);   // py0
    }
    if (t < 512) {                       // both groups' barrier counters
        __hip_atomic_store((unsigned*)(ws + 40960) + t, 0u,
                           __ATOMIC_RELAXED, __HIP_MEMORY_SCOPE_SYSTEM);
    }
}

// LDS limits us to 1 block/CU = 16 waves = 4 waves/EU; declare that to the
// register allocator so the VGPR budget is 128 (not the 8-wave default 64).
__global__ __launch_bounds__(NTHR)
__attribute__((amdgpu_waves_per_eu(4, 4)))
void sink_main(
    const float* __restrict__ xin, const float* __restrict__ yin,
    float* __restrict__ ws, float* __restrict__ out)
{
    extern __shared__ float smem[];
    float2* x01 = (float2*)smem;
    float*  x2  = smem + 8192;
    float2* y01 = (float2*)(smem + 12288);
    float*  y2  = smem + 20480;
    float*  G   = smem + 24576;
    float2* part = (float2*)(smem + 28672);

    float* f    = ws;
    float* g    = ws + 4096;
    float* px0  = ws + 8192;
    float* px1  = ws + 12288;
    float* py0  = ws + 16384;
    float* py1  = ws + 20480;
    float* ffin = ws + 24576;
    float* fxv  = ws + 28672;
    float* fyv  = ws + 32768;
    float* uls  = ws + 36864;
    unsigned* ctrA = (unsigned*)(ws + 40960);        // group A (blocks 0-127)
    unsigned* ctrB = (unsigned*)(ws + 40960) + 256;  // group B (blocks 128-255)

    const int tid  = threadIdx.x;
    const int b    = blockIdx.x;
    const int wave = tid >> 6;
    const int lane = tid & 63;
    unsigned* cbarrier = (b < 128) ? ctrA : ctrB;

    // Stage both point clouds into LDS (SoA). p_q stride 3, p_gt stride 4.
    for (int i = tid; i < NPT; i += NTHR) {
        float a0 = xin[3 * i], a1 = xin[3 * i + 1], a2v = xin[3 * i + 2];
        x01[i] = make_float2(a0, a1); x2[i] = a2v;
        float4 v = ((const float4*)yin)[i];
        y01[i] = make_float2(v.x, v.y); y2[i] = v.z;
    }
    __syncthreads();

    for (int h = 0; h <= 40; ++h) {
        // ---- decode this block's chain for this step ----
        bool rows_x, cols_x, isU = false, avg = false;
        const float* pot; float* outp; float scale = INV_E2;
        int row0g, rows_pb;
        if (h == 0) {
            if (b < 128)      { rows_x = true;  cols_x = false; pot = g;    outp = f;    rows_pb = 32; row0g = b * 32; }
            else if (b < 192) { rows_x = true;  cols_x = true;  pot = px0;  outp = px1;  avg = true; rows_pb = 64; row0g = (b - 128) * 64; }
            else              { rows_x = true;  cols_x = true;  pot = nullptr; outp = uls; isU = true; scale = S_U; rows_pb = 64; row0g = (b - 192) * 64; }
        } else if (h == 40) {
            if (b < 128)      { rows_x = true;  cols_x = false; pot = g;    outp = ffin; rows_pb = 32; row0g = b * 32; }
            else if (b < 192) { rows_x = true;  cols_x = true;  pot = px0;  outp = fxv;  rows_pb = 64; row0g = (b - 128) * 64; }
            else              { rows_x = false; cols_x = false; pot = py0;  outp = fyv;  rows_pb = 64; row0g = (b - 192) * 64; }
        } else if (h & 1) {
            int k = (h - 1) >> 1;   // yy iteration
            if (b < 128) { rows_x = false; cols_x = true;  pot = f; outp = g; rows_pb = 32; row0g = b * 32; }
            else         { rows_x = false; cols_x = false; pot = (k & 1) ? py1 : py0; outp = (k & 1) ? py0 : py1; avg = true; rows_pb = 32; row0g = (b - 128) * 32; }
        } else {
            int k = h >> 1;         // xx iteration
            if (b < 128) { rows_x = true; cols_x = false; pot = g; outp = f; rows_pb = 32; row0g = b * 32; }
            else         { rows_x = true; cols_x = true;  pot = (k & 1) ? px1 : px0; outp = (k & 1) ? px0 : px1; avg = true; rows_pb = 32; row0g = (b - 128) * 32; }
        }

        // ---- stage scaled column potential G into LDS (coherent loads) ----
        const float2* c01 = cols_x ? x01 : y01;
        const float*  c2v = cols_x ? x2  : y2;
        for (int j = tid; j < NPT; j += NTHR) {
            float2 p2 = c01[j]; float z = c2v[j];
            float cn = 0.5f * (p2.x * p2.x + p2.y * p2.y) + 0.5f * z * z;
            float pv = pot ? gload(pot + j) : 0.0f;
            G[j] = (pv - cn) * scale;
        }
        __syncthreads();

        // ---- wave tasks: 2 rows x 2048 cols each ----
        const float2* r01 = rows_x ? x01 : y01;
        const float*  r2v = rows_x ? x2  : y2;
        const int ntask = rows_pb;               // (rows_pb/2 groups) x 2 halves
        for (int t = wave; t < ntask; t += 16) {
            int grp = t >> 1, half = t & 1;
            int lr0 = grp << 1;
            int r0g = row0g + lr0;
            if (isU) run_task<true >(c01, c2v, G, r01, r2v, r0g, half, lane, scale, part, lr0);
            else     run_task<false>(c01, c2v, G, r01, r2v, r0g, half, lane, scale, part, lr0);
        }
        __syncthreads();

        // ---- finalize: merge halves, apply row term, write potential ----
        if (tid < rows_pb) {
            float2 pa = part[tid * 2 + 0], pb = part[tid * 2 + 1];
            float mm = fmaxf(pa.x, pb.x);
            float ss = pa.y * fexp2(pa.x - mm) + pb.y * fexp2(pb.x - mm);
            int rg = row0g + tid;
            float2 q = r01[rg]; float qz = r2v[rg];
            float rn = 0.5f * (q.x * q.x + q.y * q.y) + 0.5f * qz * qz;
            float lse2 = mm + flog2(ss) - rn * scale;    // + X_i
            float val;
            if (isU) {
                val = lse2;
            } else {
                val = -E2 * (lse2 - 12.0f);               // log2(4096)=12
                if (avg) val = 0.5f * (gload(pot + rg) + val);
            }
            gstore(outp + rg, val);
        }

        group_barrier(cbarrier, 128u * (unsigned)(h + 1), b);
    }

    // ---- final reduction (block 0; must also wait for group B) ----
    if (b == 0) {
        if (tid == 0) {
            for (;;) {
                unsigned tot = 0;
#pragma unroll
                for (int i = 0; i < 16; ++i)
                    tot += __hip_atomic_load(&ctrB[i * 16],
                                             __ATOMIC_RELAXED, __HIP_MEMORY_SCOPE_SYSTEM);
                if (tot >= 128u * 41u) break;
                __builtin_amdgcn_s_sleep(1);
            }
        }
        __syncthreads();

        float sf = 0.f, sg = 0.f, sx = 0.f, sy = 0.f, um = -1e30f, us = 0.f;
        for (int i = tid; i < NPT; i += NTHR) {
            sf += gload(ffin + i); sg += gload(g + i);
            sx += gload(fxv + i);  sy += gload(fyv + i);
            float v = gload(uls + i);
            float mn = fmaxf(um, v);
            us = us * fexp2(um - mn) + fexp2(v - mn);
            um = mn;
        }
#pragma unroll
        for (int off = 1; off < 64; off <<= 1) {
            sf += __shfl_xor(sf, off, 64);
            sg += __shfl_xor(sg, off, 64);
            sx += __shfl_xor(sx, off, 64);
            sy += __shfl_xor(sy, off, 64);
            float mo = __shfl_xor(um, off, 64);
            float so = __shfl_xor(us, off, 64);
            float mn = fmaxf(um, mo);
            us = us * fexp2(um - mn) + so * fexp2(mo - mn);
            um = mn;
        }
        __syncthreads();
        if (lane == 0) {
            float* red = smem;
            red[wave * 6 + 0] = sf; red[wave * 6 + 1] = sg; red[wave * 6 + 2] = sx;
            red[wave * 6 + 3] = sy; red[wave * 6 + 4] = um; red[wave * 6 + 5] = us;
        }
        __syncthreads();
        if (tid == 0) {
            float* red = smem;
            float Sf = 0, Sg = 0, Sx = 0, Sy = 0, Um = -1e30f, Us = 0;
            for (int w = 0; w < 16; ++w) {
                Sf += red[w * 6 + 0]; Sg += red[w * 6 + 1];
                Sx += red[w * 6 + 2]; Sy += red[w * 6 + 3];
                float mo = red[w * 6 + 4], so = red[w * 6 + 5];
                float mn = fmaxf(Um, mo);
                Us = Us * fexp2(Um - mn) + so * fexp2(mo - mn);
                Um = mn;
            }
            float mean = (Sf + Sg - Sx - Sy) * (1.0f / 4096.0f);
            float U = LN2F * (Um + flog2(Us)) - logf(4096.0f * 4095.0f);
            out[0] = mean + U;
        }
    }
}

extern "C" void kernel_launch(void* const* d_in, const int* in_sizes, int n_in,
                              void* d_out, int out_size, void* d_ws, size_t ws_size,
                              hipStream_t stream) {
    const float* x = (const float*)d_in[0];
    const float* y = (const float*)d_in[1];
    float* ws  = (float*)d_ws;
    float* out = (float*)d_out;

    (void)hipFuncSetAttribute((const void*)sink_main,
                              hipFuncAttributeMaxDynamicSharedMemorySize, SMEM_BYTES);

    sink_init<<<4, 1024, 0, stream>>>(ws);
    sink_main<<<NBLK, NTHR, SMEM_BYTES, stream>>>(x, y, ws, out);
}

// Round 5
// 538.888 us; speedup vs baseline: 7.7057x; 1.1516x over previous
//
#include <hip/hip_runtime.h>

#define NPT  4096
#define NBLK 256
#define NTHR 1024

constexpr float EPSV   = 1e-4f;
constexpr float LN2F   = 0.69314718055994531f;
constexpr float E2     = EPSV * LN2F;          // eps*ln2
constexpr float INV_E2 = 1.0f / E2;            // 1/(eps*ln2)
constexpr float S_U    = 4.0f / LN2F;          // uniformity scale

// LDS layout (floats):
//   packx : float4[4096]  [0,16384)      (x,y,z, Gx)  column/row pack for x
//   packy : float4[4096]  [16384,32768)  (x,y,z, Gy)  column/row pack for y
//   part  : float2[128]   [32768,33024)  (m,s) partials
// xyz are persistent; only .w (the scaled column potential G) is restaged
// per step via ds_write_b32. Main loop reads one float4 per column via a
// single ds_read_b128 with immediate offsets off one base register.
#define SMEM_FLOATS 33024
#define SMEM_BYTES  (SMEM_FLOATS * 4)

__device__ __forceinline__ float fexp2(float x) { return __builtin_amdgcn_exp2f(x); }
__device__ __forceinline__ float flog2(float x) { return __builtin_amdgcn_logf(x); }

// system-scope (sc0 sc1) relaxed accessors: bypass non-coherent XCD L2s,
// hit the coherent memory-side Infinity Cache. No wbl2/inv fences needed.
__device__ __forceinline__ float gload(const float* p) {
    return __hip_atomic_load(p, __ATOMIC_RELAXED, __HIP_MEMORY_SCOPE_SYSTEM);
}
__device__ __forceinline__ void gstore(float* p, float v) {
    __hip_atomic_store(p, v, __ATOMIC_RELAXED, __HIP_MEMORY_SCOPE_SYSTEM);
}

// Fence-free GROUP barrier (128 blocks per group; the xy chain and the
// xx/yy/uniformity chains never read each other's state inside the loop).
__device__ __forceinline__ void group_barrier(unsigned* base, unsigned target, int b) {
    asm volatile("s_waitcnt vmcnt(0)" ::: "memory");
    __syncthreads();
    if (threadIdx.x == 0) {
        __hip_atomic_fetch_add(&base[(b & 15) * 16], 1u,
                               __ATOMIC_RELAXED, __HIP_MEMORY_SCOPE_SYSTEM);
        for (;;) {
            unsigned tot = 0;
#pragma unroll
            for (int i = 0; i < 16; ++i)
                tot += __hip_atomic_load(&base[i * 16],
                                         __ATOMIC_RELAXED, __HIP_MEMORY_SCOPE_SYSTEM);
            if (tot >= target) break;
            __builtin_amdgcn_s_sleep(1);
        }
    }
    __syncthreads();
}

// One wave: chunked log2-LSE for 2 rows over 2048 columns (half of 4096).
// One ds_read_b128 per column (float4 = x,y,z,G), immediate offsets.
// Reduction: max-butterfly, single rescale, sum-butterfly (no exp in tree).
template<bool ISU>
__device__ __forceinline__ void run_task(
    const float4* __restrict__ cp,    // column pack array (LDS)
    const float4* __restrict__ rp,    // row pack array (LDS)
    int r0g, int half, int lane, float scale, float2* part, int lr0)
{
    float xs0[2], xs1[2], xs2[2];
#pragma unroll
    for (int r = 0; r < 2; ++r) {
        float4 q = rp[r0g + r];
        xs0[r] = q.x * scale; xs1[r] = q.y * scale; xs2[r] = q.z * scale;
    }
    const float4* col = cp + half * 2048 + lane;
    float m[2], s[2];

#pragma unroll
    for (int chunk = 0; chunk < 2; ++chunk) {
        float av[2][16];
        float mc[2] = {-1e30f, -1e30f};
#pragma unroll
        for (int k = 0; k < 16; ++k) {
            const float4 c = col[chunk * 1024 + k * 64];   // imm-offset b128
#pragma unroll
            for (int r = 0; r < 2; ++r) {
                float a = fmaf(xs0[r], c.x, c.w);
                a = fmaf(xs1[r], c.y, a);
                a = fmaf(xs2[r], c.z, a);
                if (ISU) {
                    const int j = half * 2048 + chunk * 1024 + k * 64 + lane;
                    a = (j == r0g + r) ? -1e30f : a;       // mask diagonal
                }
                av[r][k] = a;
                mc[r] = fmaxf(mc[r], a);
            }
        }
#pragma unroll
        for (int r = 0; r < 2; ++r) {
            float sc_ = 0.0f;
#pragma unroll
            for (int k = 0; k < 16; ++k) sc_ += fexp2(av[r][k] - mc[r]);
            if (chunk == 0) { m[r] = mc[r]; s[r] = sc_; }
            else {
                float d = m[r] - mc[r];
                float e = fexp2(-fabsf(d));                // exp2(min-max)
                float bigs   = (d >= 0.0f) ? s[r] : sc_;
                float smalls = (d >= 0.0f) ? sc_  : s[r];
                s[r] = fmaf(smalls, e, bigs);
                m[r] = fmaxf(m[r], mc[r]);
            }
        }
    }
    // ---- max-then-sum 64-lane reduction (exp-free tree) ----
    float ml[2] = {m[0], m[1]};
#pragma unroll
    for (int off = 1; off < 64; off <<= 1) {
#pragma unroll
        for (int r = 0; r < 2; ++r)
            m[r] = fmaxf(m[r], __shfl_xor(m[r], off, 64));
    }
#pragma unroll
    for (int r = 0; r < 2; ++r) s[r] *= fexp2(ml[r] - m[r]);
#pragma unroll
    for (int off = 1; off < 64; off <<= 1) {
#pragma unroll
        for (int r = 0; r < 2; ++r)
            s[r] += __shfl_xor(s[r], off, 64);
    }
    if (lane == 0) {
        part[(lr0 + 0) * 2 + half] = make_float2(m[0], s[0]);
        part[(lr0 + 1) * 2 + half] = make_float2(m[1], s[1]);
    }
}

__global__ void sink_init(float* __restrict__ ws) {
    int t = blockIdx.x * blockDim.x + threadIdx.x;
    if (t < NPT) {
        gstore(ws + t, 0.0f);           // f
        gstore(ws + 4096 + t, 0.0f);    // g
        gstore(ws + 8192 + t, 0.0f);    // px0
        gstore(ws + 16384 + t, 0.0f);   // py0
    }
    if (t < 512) {                       // both groups' barrier counters
        __hip_atomic_store((unsigned*)(ws + 40960) + t, 0u,
                           __ATOMIC_RELAXED, __HIP_MEMORY_SCOPE_SYSTEM);
    }
}

__global__ __launch_bounds__(NTHR)
__attribute__((amdgpu_waves_per_eu(4, 4)))
void sink_main(
    const float* __restrict__ xin, const float* __restrict__ yin,
    float* __restrict__ ws, float* __restrict__ out)
{
    extern __shared__ float smem[];
    float4* packx = (float4*)smem;
    float4* packy = (float4*)(smem + 16384);
    float2* part  = (float2*)(smem + 32768);

    float* f    = ws;
    float* g    = ws + 4096;
    float* px0  = ws + 8192;
    float* px1  = ws + 12288;
    float* py0  = ws + 16384;
    float* py1  = ws + 20480;
    float* ffin = ws + 24576;
    float* fxv  = ws + 28672;
    float* fyv  = ws + 32768;
    float* uls  = ws + 36864;
    unsigned* ctrA = (unsigned*)(ws + 40960);        // group A (blocks 0-127)
    unsigned* ctrB = (unsigned*)(ws + 40960) + 256;  // group B (blocks 128-255)

    const int tid  = threadIdx.x;
    const int b    = blockIdx.x;
    const int wave = tid >> 6;
    const int lane = tid & 63;
    unsigned* cbarrier = (b < 128) ? ctrA : ctrB;

    // Stage both point clouds into LDS float4 packs (w filled per step).
    for (int i = tid; i < NPT; i += NTHR) {
        packx[i] = make_float4(xin[3 * i], xin[3 * i + 1], xin[3 * i + 2], 0.0f);
        float4 v = ((const float4*)yin)[i];
        packy[i] = make_float4(v.x, v.y, v.z, 0.0f);
    }
    __syncthreads();

    for (int h = 0; h <= 40; ++h) {
        // ---- decode this block's chain for this step ----
        bool rows_x, cols_x, isU = false, avg = false;
        const float* pot; float* outp; float scale = INV_E2;
        int row0g, rows_pb;
        if (h == 0) {
            if (b < 128)      { rows_x = true;  cols_x = false; pot = g;    outp = f;    rows_pb = 32; row0g = b * 32; }
            else if (b < 192) { rows_x = true;  cols_x = true;  pot = px0;  outp = px1;  avg = true; rows_pb = 64; row0g = (b - 128) * 64; }
            else              { rows_x = true;  cols_x = true;  pot = nullptr; outp = uls; isU = true; scale = S_U; rows_pb = 64; row0g = (b - 192) * 64; }
        } else if (h == 40) {
            if (b < 128)      { rows_x = true;  cols_x = false; pot = g;    outp = ffin; rows_pb = 32; row0g = b * 32; }
            else if (b < 192) { rows_x = true;  cols_x = true;  pot = px0;  outp = fxv;  rows_pb = 64; row0g = (b - 128) * 64; }
            else              { rows_x = false; cols_x = false; pot = py0;  outp = fyv;  rows_pb = 64; row0g = (b - 192) * 64; }
        } else if (h & 1) {
            int k = (h - 1) >> 1;   // yy iteration
            if (b < 128) { rows_x = false; cols_x = true;  pot = f; outp = g; rows_pb = 32; row0g = b * 32; }
            else         { rows_x = false; cols_x = false; pot = (k & 1) ? py1 : py0; outp = (k & 1) ? py0 : py1; avg = true; rows_pb = 32; row0g = (b - 128) * 32; }
        } else {
            int k = h >> 1;         // xx iteration
            if (b < 128) { rows_x = true; cols_x = false; pot = g; outp = f; rows_pb = 32; row0g = b * 32; }
            else         { rows_x = true; cols_x = true;  pot = (k & 1) ? px1 : px0; outp = (k & 1) ? px0 : px1; avg = true; rows_pb = 32; row0g = (b - 128) * 32; }
        }

        // ---- restage only .w of the active column pack ----
        float4* colpk = cols_x ? packx : packy;
        for (int j = tid; j < NPT; j += NTHR) {
            float4 c = colpk[j];
            float cn = 0.5f * (c.x * c.x + c.y * c.y) + 0.5f * c.z * c.z;
            float pv = pot ? gload(pot + j) : 0.0f;
            colpk[j].w = (pv - cn) * scale;     // ds_write_b32
        }
        __syncthreads();

        // ---- wave tasks: 2 rows x 2048 cols each ----
        const float4* rowpk = rows_x ? packx : packy;
        const int ntask = rows_pb;               // (rows_pb/2 groups) x 2 halves
        for (int t = wave; t < ntask; t += 16) {
            int grp = t >> 1, half = t & 1;
            int lr0 = grp << 1;
            int r0g = row0g + lr0;
            if (isU) run_task<true >(colpk, rowpk, r0g, half, lane, scale, part, lr0);
            else     run_task<false>(colpk, rowpk, r0g, half, lane, scale, part, lr0);
        }
        __syncthreads();

        // ---- finalize: merge halves, apply row term, write potential ----
        if (tid < rows_pb) {
            float2 pa = part[tid * 2 + 0], pb = part[tid * 2 + 1];
            float mm = fmaxf(pa.x, pb.x);
            float ss = pa.y * fexp2(pa.x - mm) + pb.y * fexp2(pb.x - mm);
            int rg = row0g + tid;
            float4 q = rowpk[rg];
            float rn = 0.5f * (q.x * q.x + q.y * q.y) + 0.5f * q.z * q.z;
            float lse2 = mm + flog2(ss) - rn * scale;    // + X_i
            float val;
            if (isU) {
                val = lse2;
            } else {
                val = -E2 * (lse2 - 12.0f);               // log2(4096)=12
                if (avg) val = 0.5f * (gload(pot + rg) + val);
            }
            gstore(outp + rg, val);
        }

        group_barrier(cbarrier, 128u * (unsigned)(h + 1), b);
    }

    // ---- final reduction (block 0; must also wait for group B) ----
    if (b == 0) {
        if (tid == 0) {
            for (;;) {
                unsigned tot = 0;
#pragma unroll
                for (int i = 0; i < 16; ++i)
                    tot += __hip_atomic_load(&ctrB[i * 16],
                                             __ATOMIC_RELAXED, __HIP_MEMORY_SCOPE_SYSTEM);
                if (tot >= 128u * 41u) break;
                __builtin_amdgcn_s_sleep(1);
            }
        }
        __syncthreads();

        float sf = 0.f, sg = 0.f, sx = 0.f, sy = 0.f, um = -1e30f, us = 0.f;
        for (int i = tid; i < NPT; i += NTHR) {
            sf += gload(ffin + i); sg += gload(g + i);
            sx += gload(fxv + i);  sy += gload(fyv + i);
            float v = gload(uls + i);
            float mn = fmaxf(um, v);
            us = us * fexp2(um - mn) + fexp2(v - mn);
            um = mn;
        }
#pragma unroll
        for (int off = 1; off < 64; off <<= 1) {
            sf += __shfl_xor(sf, off, 64);
            sg += __shfl_xor(sg, off, 64);
            sx += __shfl_xor(sx, off, 64);
            sy += __shfl_xor(sy, off, 64);
            float mo = __shfl_xor(um, off, 64);
            float so = __shfl_xor(us, off, 64);
            float mn = fmaxf(um, mo);
            us = us * fexp2(um - mn) + so * fexp2(mo - mn);
            um = mn;
        }
        __syncthreads();
        if (lane == 0) {
            float* red = smem;
            red[wave * 6 + 0] = sf; red[wave * 6 + 1] = sg; red[wave * 6 + 2] = sx;
            red[wave * 6 + 3] = sy; red[wave * 6 + 4] = um; red[wave * 6 + 5] = us;
        }
        __syncthreads();
        if (tid == 0) {
            float* red = smem;
            float Sf = 0, Sg = 0, Sx = 0, Sy = 0, Um = -1e30f, Us = 0;
            for (int w = 0; w < 16; ++w) {
                Sf += red[w * 6 + 0]; Sg += red[w * 6 + 1];
                Sx += red[w * 6 + 2]; Sy += red[w * 6 + 3];
                float mo = red[w * 6 + 4], so = red[w * 6 + 5];
                float mn = fmaxf(Um, mo);
                Us = Us * fexp2(Um - mn) + so * fexp2(mo - mn);
                Um = mn;
            }
            float mean = (Sf + Sg - Sx - Sy) * (1.0f / 4096.0f);
            float U = LN2F * (Um + flog2(Us)) - logf(4096.0f * 4095.0f);
            out[0] = mean + U;
        }
    }
}

extern "C" void kernel_launch(void* const* d_in, const int* in_sizes, int n_in,
                              void* d_out, int out_size, void* d_ws, size_t ws_size,
                              hipStream_t stream) {
    const float* x = (const float*)d_in[0];
    const float* y = (const float*)d_in[1];
    float* ws  = (float*)d_ws;
    float* out = (float*)d_out;

    (void)hipFuncSetAttribute((const void*)sink_main,
                              hipFuncAttributeMaxDynamicSharedMemorySize, SMEM_BYTES);

    sink_init<<<4, 1024, 0, stream>>>(ws);
    sink_main<<<NBLK, NTHR, SMEM_BYTES, stream>>>(x, y, ws, out);
}

// Round 6
// 535.267 us; speedup vs baseline: 7.7578x; 1.0068x over previous
//
#include <hip/hip_runtime.h>

#define NPT  4096
#define NBLK 256
#define NTHR 1024

constexpr float EPSV   = 1e-4f;
constexpr float LN2F   = 0.69314718055994531f;
constexpr float E2     = EPSV * LN2F;          // eps*ln2
constexpr float INV_E2 = 1.0f / E2;            // 1/(eps*ln2)
constexpr float S_U    = 4.0f / LN2F;          // uniformity scale

// LDS layout (floats), column-PAIR packed for v_pk_*_f32 dual-issue:
//   pAx : float4[2048] [0,8192)      (x0,x1,y0,y1) of x-point pairs
//   pBx : float4[2048] [8192,16384)  (z0,z1,G0,G1) of x-point pairs
//   pAy : float4[2048] [16384,24576) (x0,x1,y0,y1) of y-point pairs
//   pBy : float4[2048] [24576,32768) (z0,z1,G0,G1) of y-point pairs
//   part: float2[128]  [32768,33024) (m,s) partials
// xyz persistent; only G (pB[].zw) restaged per step via ds_write_b64.
#define SMEM_FLOATS 33024
#define SMEM_BYTES  (SMEM_FLOATS * 4)

typedef float v2f __attribute__((ext_vector_type(2)));

__device__ __forceinline__ float fexp2(float x) { return __builtin_amdgcn_exp2f(x); }
__device__ __forceinline__ float flog2(float x) { return __builtin_amdgcn_logf(x); }

__device__ __forceinline__ v2f pk_fma(v2f a, v2f b, v2f c) {
    v2f d;
    asm("v_pk_fma_f32 %0, %1, %2, %3" : "=v"(d) : "v"(a), "v"(b), "v"(c));
    return d;
}
__device__ __forceinline__ v2f pk_add(v2f a, v2f b) {
    v2f d;
    asm("v_pk_add_f32 %0, %1, %2" : "=v"(d) : "v"(a), "v"(b));
    return d;
}
__device__ __forceinline__ float max3f(float a, float b, float c) {
    float d;
    asm("v_max3_f32 %0, %1, %2, %3" : "=v"(d) : "v"(a), "v"(b), "v"(c));
    return d;
}

// system-scope (sc0 sc1) relaxed accessors: bypass non-coherent XCD L2s.
__device__ __forceinline__ float gload(const float* p) {
    return __hip_atomic_load(p, __ATOMIC_RELAXED, __HIP_MEMORY_SCOPE_SYSTEM);
}
__device__ __forceinline__ void gstore(float* p, float v) {
    __hip_atomic_store(p, v, __ATOMIC_RELAXED, __HIP_MEMORY_SCOPE_SYSTEM);
}

// Fence-free GROUP barrier (128 blocks per group).
__device__ __forceinline__ void group_barrier(unsigned* base, unsigned target, int b) {
    asm volatile("s_waitcnt vmcnt(0)" ::: "memory");
    __syncthreads();
    if (threadIdx.x == 0) {
        __hip_atomic_fetch_add(&base[(b & 15) * 16], 1u,
                               __ATOMIC_RELAXED, __HIP_MEMORY_SCOPE_SYSTEM);
        for (;;) {
            unsigned tot = 0;
#pragma unroll
            for (int i = 0; i < 16; ++i)
                tot += __hip_atomic_load(&base[i * 16],
                                         __ATOMIC_RELAXED, __HIP_MEMORY_SCOPE_SYSTEM);
            if (tot >= target) break;
            __builtin_amdgcn_s_sleep(1);
        }
    }
    __syncthreads();
}

// One wave: log2-LSE for 2 rows over 2048 columns (1024 column-pairs).
// Per pair: 2x ds_read_b128; per pair per row: 3 pk_fma + 1 max3 +
// 1 pk_add + 2 exp2 + 2 add. Chunk = 4 pairs (av[2][4] v2f = 16 VGPR).
template<bool ISU>
__device__ __forceinline__ void run_task(
    const float4* __restrict__ cpA, const float4* __restrict__ cpB,
    const float*  __restrict__ rAf, const float*  __restrict__ rBf,
    int r0g, int half, int lane, float scale, float2* part, int lr0)
{
    v2f xs0[2], xs1[2], xs2[2];
#pragma unroll
    for (int r = 0; r < 2; ++r) {
        const int rr = r0g + r;
        const int pb4 = (rr >> 1) * 4, c0 = rr & 1;
        float xv = rAf[pb4 + c0] * scale;
        float yv = rAf[pb4 + 2 + c0] * scale;
        float zv = rBf[pb4 + c0] * scale;
        xs0[r].x = xv; xs0[r].y = xv;
        xs1[r].x = yv; xs1[r].y = yv;
        xs2[r].x = zv; xs2[r].y = zv;
    }
    float m[2], s[2];
    const int pbase = half * 1024 + lane;
    const float4* colA = cpA + pbase;
    const float4* colB = cpB + pbase;

#pragma unroll
    for (int chunk = 0; chunk < 4; ++chunk) {
        v2f av[2][4];
        float mc[2] = {-1e30f, -1e30f};
#pragma unroll
        for (int k = 0; k < 4; ++k) {
            const float4 a4 = colA[(chunk * 4 + k) * 64];
            const float4 b4 = colB[(chunk * 4 + k) * 64];
            v2f xx; xx.x = a4.x; xx.y = a4.y;
            v2f yy; yy.x = a4.z; yy.y = a4.w;
            v2f zz; zz.x = b4.x; zz.y = b4.y;
            v2f gg; gg.x = b4.z; gg.y = b4.w;
#pragma unroll
            for (int r = 0; r < 2; ++r) {
                v2f a01 = pk_fma(xs2[r], zz, gg);
                a01 = pk_fma(xs1[r], yy, a01);
                a01 = pk_fma(xs0[r], xx, a01);
                if (ISU) {
                    const int p = pbase + (chunk * 4 + k) * 64;
                    const int rr = r0g + r;
                    if (p == (rr >> 1)) {
                        if (rr & 1) a01.y = -1e30f; else a01.x = -1e30f;
                    }
                }
                av[r][k] = a01;
                mc[r] = max3f(mc[r], a01.x, a01.y);
            }
        }
#pragma unroll
        for (int r = 0; r < 2; ++r) {
            const float nm = -mc[r];
            v2f mcn; mcn.x = nm; mcn.y = nm;
            float sA = 0.0f, sB = 0.0f;
#pragma unroll
            for (int k = 0; k < 4; ++k) {
                v2f d = pk_add(av[r][k], mcn);
                sA += fexp2(d.x);
                sB += fexp2(d.y);
            }
            const float sc_ = sA + sB;
            if (chunk == 0) { m[r] = mc[r]; s[r] = sc_; }
            else {
                float dd = m[r] - mc[r];
                float e = fexp2(-fabsf(dd));
                float bigs   = (dd >= 0.0f) ? s[r] : sc_;
                float smalls = (dd >= 0.0f) ? sc_  : s[r];
                s[r] = fmaf(smalls, e, bigs);
                m[r] = fmaxf(m[r], mc[r]);
            }
        }
    }
    // ---- max-then-sum 64-lane reduction (exp-free trees) ----
    float ml[2] = {m[0], m[1]};
#pragma unroll
    for (int off = 1; off < 64; off <<= 1) {
#pragma unroll
        for (int r = 0; r < 2; ++r)
            m[r] = fmaxf(m[r], __shfl_xor(m[r], off, 64));
    }
#pragma unroll
    for (int r = 0; r < 2; ++r) s[r] *= fexp2(ml[r] - m[r]);
#pragma unroll
    for (int off = 1; off < 64; off <<= 1) {
#pragma unroll
        for (int r = 0; r < 2; ++r)
            s[r] += __shfl_xor(s[r], off, 64);
    }
    if (lane == 0) {
        part[(lr0 + 0) * 2 + half] = make_float2(m[0], s[0]);
        part[(lr0 + 1) * 2 + half] = make_float2(m[1], s[1]);
    }
}

__global__ void sink_init(float* __restrict__ ws) {
    int t = blockIdx.x * blockDim.x + threadIdx.x;
    if (t < NPT) {
        gstore(ws + t, 0.0f);           // f
        gstore(ws + 4096 + t, 0.0f);    // g
        gstore(ws + 8192 + t, 0.0f);    // px0
        gstore(ws + 16384 + t, 0.0f);   // py0
    }
    if (t < 512) {
        __hip_atomic_store((unsigned*)(ws + 40960) + t, 0u,
                           __ATOMIC_RELAXED, __HIP_MEMORY_SCOPE_SYSTEM);
    }
}

__global__ __launch_bounds__(NTHR)
__attribute__((amdgpu_waves_per_eu(4, 4)))
void sink_main(
    const float* __restrict__ xin, const float* __restrict__ yin,
    float* __restrict__ ws, float* __restrict__ out)
{
    extern __shared__ float smem[];
    float4* pAx = (float4*)smem;
    float4* pBx = (float4*)(smem + 8192);
    float4* pAy = (float4*)(smem + 16384);
    float4* pBy = (float4*)(smem + 24576);
    float2* part = (float2*)(smem + 32768);

    float* f    = ws;
    float* g    = ws + 4096;
    float* px0  = ws + 8192;
    float* px1  = ws + 12288;
    float* py0  = ws + 16384;
    float* py1  = ws + 20480;
    float* ffin = ws + 24576;
    float* fxv  = ws + 28672;
    float* fyv  = ws + 32768;
    float* uls  = ws + 36864;
    unsigned* ctrA = (unsigned*)(ws + 40960);        // group A (blocks 0-127)
    unsigned* ctrB = (unsigned*)(ws + 40960) + 256;  // group B (blocks 128-255)

    const int tid  = threadIdx.x;
    const int b    = blockIdx.x;
    const int wave = tid >> 6;
    const int lane = tid & 63;
    unsigned* cbarrier = (b < 128) ? ctrA : ctrB;

    // Stage point clouds into pair-packed LDS (G slots filled per step).
    const float4* yin4 = (const float4*)yin;
    for (int i = tid; i < 2048; i += NTHR) {
        float x0 = xin[6 * i + 0], y0v = xin[6 * i + 1], z0 = xin[6 * i + 2];
        float x1 = xin[6 * i + 3], y1v = xin[6 * i + 4], z1 = xin[6 * i + 5];
        pAx[i] = make_float4(x0, x1, y0v, y1v);
        pBx[i] = make_float4(z0, z1, 0.0f, 0.0f);
        float4 v0 = yin4[2 * i], v1 = yin4[2 * i + 1];
        pAy[i] = make_float4(v0.x, v1.x, v0.y, v1.y);
        pBy[i] = make_float4(v0.z, v1.z, 0.0f, 0.0f);
    }
    __syncthreads();

    for (int h = 0; h <= 40; ++h) {
        // ---- decode this block's chain for this step ----
        bool rows_x, cols_x, isU = false, avg = false;
        const float* pot; float* outp; float scale = INV_E2;
        int row0g, rows_pb;
        if (h == 0) {
            if (b < 128)      { rows_x = true;  cols_x = false; pot = g;    outp = f;    rows_pb = 32; row0g = b * 32; }
            else if (b < 192) { rows_x = true;  cols_x = true;  pot = px0;  outp = px1;  avg = true; rows_pb = 64; row0g = (b - 128) * 64; }
            else              { rows_x = true;  cols_x = true;  pot = nullptr; outp = uls; isU = true; scale = S_U; rows_pb = 64; row0g = (b - 192) * 64; }
        } else if (h == 40) {
            if (b < 128)      { rows_x = true;  cols_x = false; pot = g;    outp = ffin; rows_pb = 32; row0g = b * 32; }
            else if (b < 192) { rows_x = true;  cols_x = true;  pot = px0;  outp = fxv;  rows_pb = 64; row0g = (b - 128) * 64; }
            else              { rows_x = false; cols_x = false; pot = py0;  outp = fyv;  rows_pb = 64; row0g = (b - 192) * 64; }
        } else if (h & 1) {
            int k = (h - 1) >> 1;   // yy iteration
            if (b < 128) { rows_x = false; cols_x = true;  pot = f; outp = g; rows_pb = 32; row0g = b * 32; }
            else         { rows_x = false; cols_x = false; pot = (k & 1) ? py1 : py0; outp = (k & 1) ? py0 : py1; avg = true; rows_pb = 32; row0g = (b - 128) * 32; }
        } else {
            int k = h >> 1;         // xx iteration
            if (b < 128) { rows_x = true; cols_x = false; pot = g; outp = f; rows_pb = 32; row0g = b * 32; }
            else         { rows_x = true; cols_x = true;  pot = (k & 1) ? px1 : px0; outp = (k & 1) ? px0 : px1; avg = true; rows_pb = 32; row0g = (b - 128) * 32; }
        }

        // ---- restage G pair (pB[].zw) of the active column pack ----
        float4* cpA = cols_x ? pAx : pAy;
        float4* cpB = cols_x ? pBx : pBy;
        for (int p = tid; p < 2048; p += NTHR) {
            float4 a4 = cpA[p];
            float4 b4 = cpB[p];
            float cn0 = 0.5f * (a4.x * a4.x + a4.z * a4.z + b4.x * b4.x);
            float cn1 = 0.5f * (a4.y * a4.y + a4.w * a4.w + b4.y * b4.y);
            float pv0 = pot ? gload(pot + 2 * p)     : 0.0f;
            float pv1 = pot ? gload(pot + 2 * p + 1) : 0.0f;
            ((float2*)&cpB[p])[1] = make_float2((pv0 - cn0) * scale,
                                                (pv1 - cn1) * scale);
        }
        __syncthreads();

        // ---- wave tasks: 2 rows x 2048 cols each ----
        const float* rAf = (const float*)(rows_x ? pAx : pAy);
        const float* rBf = (const float*)(rows_x ? pBx : pBy);
        const int ntask = rows_pb;
        for (int t = wave; t < ntask; t += 16) {
            int grp = t >> 1, half = t & 1;
            int lr0 = grp << 1;
            int r0g = row0g + lr0;
            if (isU) run_task<true >(cpA, cpB, rAf, rBf, r0g, half, lane, scale, part, lr0);
            else     run_task<false>(cpA, cpB, rAf, rBf, r0g, half, lane, scale, part, lr0);
        }
        __syncthreads();

        // ---- finalize: merge halves, apply row term, write potential ----
        if (tid < rows_pb) {
            float2 pa = part[tid * 2 + 0], pb = part[tid * 2 + 1];
            float mm = fmaxf(pa.x, pb.x);
            float ss = pa.y * fexp2(pa.x - mm) + pb.y * fexp2(pb.x - mm);
            int rg = row0g + tid;
            const int pb4 = (rg >> 1) * 4, c0 = rg & 1;
            float xv = rAf[pb4 + c0];
            float yv = rAf[pb4 + 2 + c0];
            float zv = rBf[pb4 + c0];
            float rn = 0.5f * (xv * xv + yv * yv + zv * zv);
            float lse2 = mm + flog2(ss) - rn * scale;    // + X_i
            float val;
            if (isU) {
                val = lse2;
            } else {
                val = -E2 * (lse2 - 12.0f);               // log2(4096)=12
                if (avg) val = 0.5f * (gload(pot + rg) + val);
            }
            gstore(outp + rg, val);
        }

        group_barrier(cbarrier, 128u * (unsigned)(h + 1), b);
    }

    // ---- final reduction (block 0; must also wait for group B) ----
    if (b == 0) {
        if (tid == 0) {
            for (;;) {
                unsigned tot = 0;
#pragma unroll
                for (int i = 0; i < 16; ++i)
                    tot += __hip_atomic_load(&ctrB[i * 16],
                                             __ATOMIC_RELAXED, __HIP_MEMORY_SCOPE_SYSTEM);
                if (tot >= 128u * 41u) break;
                __builtin_amdgcn_s_sleep(1);
            }
        }
        __syncthreads();

        float sf = 0.f, sg = 0.f, sx = 0.f, sy = 0.f, um = -1e30f, us = 0.f;
        for (int i = tid; i < NPT; i += NTHR) {
            sf += gload(ffin + i); sg += gload(g + i);
            sx += gload(fxv + i);  sy += gload(fyv + i);
            float v = gload(uls + i);
            float mn = fmaxf(um, v);
            us = us * fexp2(um - mn) + fexp2(v - mn);
            um = mn;
        }
#pragma unroll
        for (int off = 1; off < 64; off <<= 1) {
            sf += __shfl_xor(sf, off, 64);
            sg += __shfl_xor(sg, off, 64);
            sx += __shfl_xor(sx, off, 64);
            sy += __shfl_xor(sy, off, 64);
            float mo = __shfl_xor(um, off, 64);
            float so = __shfl_xor(us, off, 64);
            float mn = fmaxf(um, mo);
            us = us * fexp2(um - mn) + so * fexp2(mo - mn);
            um = mn;
        }
        __syncthreads();
        if (lane == 0) {
            float* red = smem;
            red[wave * 6 + 0] = sf; red[wave * 6 + 1] = sg; red[wave * 6 + 2] = sx;
            red[wave * 6 + 3] = sy; red[wave * 6 + 4] = um; red[wave * 6 + 5] = us;
        }
        __syncthreads();
        if (tid == 0) {
            float* red = smem;
            float Sf = 0, Sg = 0, Sx = 0, Sy = 0, Um = -1e30f, Us = 0;
            for (int w = 0; w < 16; ++w) {
                Sf += red[w * 6 + 0]; Sg += red[w * 6 + 1];
                Sx += red[w * 6 + 2]; Sy += red[w * 6 + 3];
                float mo = red[w * 6 + 4], so = red[w * 6 + 5];
                float mn = fmaxf(Um, mo);
                Us = Us * fexp2(Um - mn) + so * fexp2(mo - mn);
                Um = mn;
            }
            float mean = (Sf + Sg - Sx - Sy) * (1.0f / 4096.0f);
            float U = LN2F * (Um + flog2(Us)) - logf(4096.0f * 4095.0f);
            out[0] = mean + U;
        }
    }
}

extern "C" void kernel_launch(void* const* d_in, const int* in_sizes, int n_in,
                              void* d_out, int out_size, void* d_ws, size_t ws_size,
                              hipStream_t stream) {
    const float* x = (const float*)d_in[0];
    const float* y = (const float*)d_in[1];
    float* ws  = (float*)d_ws;
    float* out = (float*)d_out;

    (void)hipFuncSetAttribute((const void*)sink_main,
                              hipFuncAttributeMaxDynamicSharedMemorySize, SMEM_BYTES);

    sink_init<<<4, 1024, 0, stream>>>(ws);
    sink_main<<<NBLK, NTHR, SMEM_BYTES, stream>>>(x, y, ws, out);
}